// Round 2
// baseline (377.214 us; speedup 1.0000x reference)
//
#include <hip/hip_runtime.h>

// GAT fused pipeline, fp16 MFMA (16x16x32), MI355X gfx950.
// B=16, N=1024, F_in=F_out=256, H=8, ALPHA=0.2
//
// ws layout:
//   [0, 64MB)        WhT fp16  [B][H][F_out][N]   (Wh transposed)
//   +67108864        ei  f32   [B*H*N]
//   +67633152        ej  f32   [B*H*N]
//   +68157440        s   f32   [B*H*N]   s = m*log2e + log2(l)
// total 68,681,728 bytes.

#define FIN  256
#define FOUT 256
#define NN   1024
#define HH   8
#define L2E  1.442695041f

typedef _Float16 half8 __attribute__((ext_vector_type(8)));
typedef __fp16 fp16x2 __attribute__((ext_vector_type(2)));
typedef float floatx4 __attribute__((ext_vector_type(4)));

#if __has_builtin(__builtin_amdgcn_exp2f)
#define EXP2F(x) __builtin_amdgcn_exp2f(x)
#else
#define EXP2F(x) exp2f(x)
#endif

static __device__ inline unsigned int pack2(float a, float b) {
    fp16x2 h = __builtin_amdgcn_cvt_pkrtz(a, b);
    return __builtin_bit_cast(unsigned int, h);
}

// ---------------------------------------------------------------------------
// Stage 1: WhT[b,h,o,n] = sum_f W[h,o,f]*h[b,n,f] + bW[h,o]   (fp16 out)
// GEMM: M=o(256 full), Ntile=bn(128), K=f(256), BK=32. 512 thr = 8 waves.
// A = W[h] (contig f), B = h (contig f): both natural for MFMA frags.
// D-frag col(lane&15) = bn -> coalesced stores into WhT rows.
__global__ __launch_bounds__(512, 2) void wh_kernel(
    const float* __restrict__ hin, const float* __restrict__ W,
    const float* __restrict__ bW, _Float16* __restrict__ WhT)
{
    const int bnt  = blockIdx.x;   // 0..127
    const int head = blockIdx.y;   // 0..7
    const int t    = threadIdx.x;
    const int wave = t >> 6, lane = t & 63;
    const int l15 = lane & 15, quad = lane >> 4;

    __shared__ _Float16 Asm[256 * 40];  // W tile [o][kk], pitch 40 f16 (80B)
    __shared__ _Float16 Bsm[128 * 40];  // h tile [n][kk], pitch 40
    __shared__ float bWs[256];
    if (t < 256) bWs[t] = bW[head * FOUT + t];

    const int bn0 = bnt * 128;
    floatx4 acc[4][4];
#pragma unroll
    for (int a = 0; a < 4; a++)
#pragma unroll
        for (int b = 0; b < 4; b++) acc[a][b] = (floatx4)0.0f;

    const int wm = (wave & 3) * 4;   // of 16 m-tiles (o)
    const int wn = (wave >> 2) * 4;  // of 8 n-tiles (bn)

    const int ao = t >> 1, ahalf = (t & 1) * 16;   // A staging: 16 floats
    const int bnr = t >> 2, bq = (t & 3) * 8;      // B staging: 8 floats
    const float* Wrow = W + (size_t)(head * FOUT + ao) * FIN + ahalf;
    const float* hrow = hin + (size_t)(bn0 + bnr) * FIN + bq;

    for (int f0 = 0; f0 < FIN; f0 += 32) {
        __syncthreads();
        {   // stage A (W -> fp16)
            const float4* p4 = (const float4*)(Wrow + f0);
            float4 v0 = p4[0], v1 = p4[1], v2 = p4[2], v3 = p4[3];
            uint4* dst = (uint4*)((char*)Asm + ao * 80 + ahalf * 2);
            dst[0] = make_uint4(pack2(v0.x, v0.y), pack2(v0.z, v0.w),
                                pack2(v1.x, v1.y), pack2(v1.z, v1.w));
            dst[1] = make_uint4(pack2(v2.x, v2.y), pack2(v2.z, v2.w),
                                pack2(v3.x, v3.y), pack2(v3.z, v3.w));
        }
        {   // stage B (h -> fp16)
            const float4* p4 = (const float4*)(hrow + f0);
            float4 v0 = p4[0], v1 = p4[1];
            uint4* dst = (uint4*)((char*)Bsm + bnr * 80 + bq * 2);
            dst[0] = make_uint4(pack2(v0.x, v0.y), pack2(v0.z, v0.w),
                                pack2(v1.x, v1.y), pack2(v1.z, v1.w));
        }
        __syncthreads();
        half8 af[4], bf[4];
#pragma unroll
        for (int a = 0; a < 4; a++)
            af[a] = *(const half8*)((char*)Asm + ((wm + a) * 16 + l15) * 80 + quad * 16);
#pragma unroll
        for (int b = 0; b < 4; b++)
            bf[b] = *(const half8*)((char*)Bsm + ((wn + b) * 16 + l15) * 80 + quad * 16);
#pragma unroll
        for (int a = 0; a < 4; a++)
#pragma unroll
            for (int b = 0; b < 4; b++)
                acc[a][b] = __builtin_amdgcn_mfma_f32_16x16x32_f16(af[a], bf[b], acc[a][b], 0, 0, 0);
    }

    // epilogue: +bW, cvt fp16, store WhT[b,head,o,n] (n contiguous per quad)
#pragma unroll
    for (int a = 0; a < 4; a++) {
#pragma unroll
        for (int b = 0; b < 4; b++) {
            int bn = bn0 + (wn + b) * 16 + l15;
            int bidx = bn >> 10, n = bn & 1023;
#pragma unroll
            for (int r = 0; r < 4; r++) {
                int o = (wm + a) * 16 + quad * 4 + r;
                float v = acc[a][b][r] + bWs[o];
                WhT[(((size_t)(bidx * HH + head) * FOUT + o) << 10) + n] = (_Float16)v;
            }
        }
    }
}

// ---------------------------------------------------------------------------
// Stage 2a: ei[bh,n] = sum_o WhT[bh,o,n]*a1[h,o];  ej likewise with a2.
__global__ __launch_bounds__(256) void eiej_kernel(
    const _Float16* __restrict__ WhT, const float* __restrict__ a1,
    const float* __restrict__ a2, float* __restrict__ ei, float* __restrict__ ej)
{
    const int chunk = blockIdx.x;  // 0..3
    const int bh = blockIdx.y;     // 0..127
    const int head = bh & 7;
    const int t = threadIdx.x;
    __shared__ float a1s[256], a2s[256];
    a1s[t] = a1[head * 256 + t];
    a2s[t] = a2[head * 256 + t];
    __syncthreads();
    const int n = chunk * 256 + t;
    const _Float16* base = WhT + ((size_t)bh << 18) + n;
    float s1 = 0.f, s2 = 0.f;
#pragma unroll 4
    for (int o = 0; o < 256; o++) {
        float w = (float)base[(size_t)o << 10];
        s1 = fmaf(w, a1s[o], s1);
        s2 = fmaf(w, a2s[o], s2);
    }
    ei[bh * 1024 + n] = s1;
    ej[bh * 1024 + n] = s2;
}

// ---------------------------------------------------------------------------
// Stage 2b: per row i: m = lrelu(ci + ejmax), l = sum_j exp(lrelu(ci+ej[j])-m)
//           s = m*log2e + log2(l).  ci = ei[i] + bA[h].
__global__ __launch_bounds__(256) void ml_kernel(
    const float* __restrict__ ei, const float* __restrict__ ej,
    const float* __restrict__ bA, float* __restrict__ sarr)
{
    const int it = blockIdx.x;   // i-chunk of 128
    const int bh = blockIdx.y;
    const int head = bh & 7;
    const int t = threadIdx.x;
    __shared__ float ejs[1024];
    __shared__ float red[256];
    const float* ejrow = ej + bh * 1024;
    float mx = -1e30f;
#pragma unroll
    for (int k = 0; k < 4; k++) {
        float v = ejrow[t + k * 256];
        ejs[t + k * 256] = v;
        mx = fmaxf(mx, v);
    }
    red[t] = mx;
    __syncthreads();
    for (int sft = 128; sft > 0; sft >>= 1) {
        if (t < sft) red[t] = fmaxf(red[t], red[t + sft]);
        __syncthreads();
    }
    const float ejmax = red[0];
    __syncthreads();

    const int i = it * 128 + (t & 127);
    const int half = t >> 7;
    const float ci = ei[bh * 1024 + i] + bA[head];
    float tm = ci + ejmax;
    float m = fmaxf(tm, 0.2f * tm);
    float sum = 0.f;
    const int j0 = half * 512;
    for (int j = j0; j < j0 + 512; j++) {
        float e = ci + ejs[j];
        float lr = fmaxf(e, 0.2f * e);
        sum += EXP2F((lr - m) * L2E);
    }
    red[t] = sum;
    __syncthreads();
    if (t < 128) {
        float l = red[t] + red[t + 128];
        sarr[bh * 1024 + i] = m * L2E + __log2f(l);
    }
}

// ---------------------------------------------------------------------------
// Stage 3: out[b,i,h*256+o] = sigmoid(relu( sum_j p_ij * Wh[j,o] ))
// p_ij = exp2(lrelu(ci+ej[j])*log2e - s_i), generated on the fly into LDS.
// Tile 128(i) x 256(o), K=1024(j) in BK=32. 512 thr = 8 waves.
__global__ __launch_bounds__(512, 2) void pv_kernel(
    const _Float16* __restrict__ WhT, const float* __restrict__ ei,
    const float* __restrict__ ej, const float* __restrict__ sarr,
    const float* __restrict__ bA, float* __restrict__ out)
{
    const int it = blockIdx.x;   // i-tile 0..7
    const int bh = blockIdx.y;   // 0..127
    const int b = bh >> 3, head = bh & 7;
    const int t = threadIdx.x;
    const int wave = t >> 6, lane = t & 63;
    const int l15 = lane & 15, quad = lane >> 4;

    __shared__ _Float16 Ap[128 * 40];   // P tile [i][kk], pitch 40
    __shared__ _Float16 Bp[256 * 40];   // WhT tile [o][kk], pitch 40
    __shared__ float ejs[1024];

    const float* ejrow = ej + bh * 1024;
    for (int k = t; k < 1024; k += 512) ejs[k] = ejrow[k];

    const int i0 = it * 128;
    const int irow = t & 127;        // p-compute row
    const int kk8 = (t >> 7) * 8;    // p-compute kk base: 0/8/16/24
    const int gi = i0 + irow;
    const float ci = ei[bh * 1024 + gi] + bA[head];
    const float ns = -sarr[bh * 1024 + gi];

    const int bo = t >> 1;            // B staging row (o): 0..255
    const int bhalf = (t & 1) * 16;   // 16 f16 per thread
    const _Float16* wrow = WhT + ((size_t)bh << 18) + ((size_t)bo << 10) + bhalf;

    floatx4 acc[2][8];
#pragma unroll
    for (int a = 0; a < 2; a++)
#pragma unroll
        for (int c = 0; c < 8; c++) acc[a][c] = (floatx4)0.0f;

    const int wm = (wave >> 1) * 2;  // of 8 m-tiles
    const int wn = (wave & 1) * 8;   // of 16 n-tiles

    for (int j0 = 0; j0 < 1024; j0 += 32) {
        __syncthreads();
        {   // stage P tile
            float p[8];
#pragma unroll
            for (int u = 0; u < 8; u++) {
                float e = ci + ejs[j0 + kk8 + u];
                float lr = fmaxf(e, 0.2f * e);
                p[u] = EXP2F(fmaf(lr, L2E, ns));
            }
            uint4* dst = (uint4*)((char*)Ap + irow * 80 + kk8 * 2);
            *dst = make_uint4(pack2(p[0], p[1]), pack2(p[2], p[3]),
                              pack2(p[4], p[5]), pack2(p[6], p[7]));
        }
        {   // stage B tile (fp16 direct copy)
            const uint4* src = (const uint4*)(wrow + j0);
            uint4 v0 = src[0], v1 = src[1];
            uint4* dst = (uint4*)((char*)Bp + bo * 80 + bhalf * 2);
            dst[0] = v0; dst[1] = v1;
        }
        __syncthreads();
        half8 af[2], bf[8];
#pragma unroll
        for (int a = 0; a < 2; a++)
            af[a] = *(const half8*)((char*)Ap + ((wm + a) * 16 + l15) * 80 + quad * 16);
#pragma unroll
        for (int c = 0; c < 8; c++)
            bf[c] = *(const half8*)((char*)Bp + ((wn + c) * 16 + l15) * 80 + quad * 16);
#pragma unroll
        for (int a = 0; a < 2; a++)
#pragma unroll
            for (int c = 0; c < 8; c++)
                acc[a][c] = __builtin_amdgcn_mfma_f32_16x16x32_f16(af[a], bf[c], acc[a][c], 0, 0, 0);
    }

    // epilogue: relu + sigmoid, out[b, i, head*256 + o]
#pragma unroll
    for (int a = 0; a < 2; a++) {
#pragma unroll
        for (int c = 0; c < 8; c++) {
            int o = (wn + c) * 16 + l15;
#pragma unroll
            for (int r = 0; r < 4; r++) {
                int i = i0 + (wm + a) * 16 + quad * 4 + r;
                float v = acc[a][c][r];
                float rl = fmaxf(v, 0.0f);
                float y = 1.0f / (1.0f + EXP2F(-rl * L2E));
                out[((size_t)(b * 1024 + i) << 11) + head * 256 + o] = y;
            }
        }
    }
}

// ---------------------------------------------------------------------------
extern "C" void kernel_launch(void* const* d_in, const int* in_sizes, int n_in,
                              void* d_out, int out_size, void* d_ws, size_t ws_size,
                              hipStream_t stream)
{
    const float* h  = (const float*)d_in[0];
    const float* W  = (const float*)d_in[1];
    const float* bW = (const float*)d_in[2];
    const float* a1 = (const float*)d_in[3];
    const float* a2 = (const float*)d_in[4];
    const float* bA = (const float*)d_in[5];
    float* out = (float*)d_out;

    char* ws = (char*)d_ws;
    _Float16* WhT = (_Float16*)ws;                       // 67108864 B
    float* ei = (float*)(ws + 67108864);
    float* ej = (float*)(ws + 67108864 + 524288);
    float* sA = (float*)(ws + 67108864 + 2 * 524288);

    hipLaunchKernelGGL(wh_kernel,  dim3(128, 8),  dim3(512), 0, stream, h, W, bW, WhT);
    hipLaunchKernelGGL(eiej_kernel, dim3(4, 128), dim3(256), 0, stream, WhT, a1, a2, ei, ej);
    hipLaunchKernelGGL(ml_kernel,  dim3(8, 128),  dim3(256), 0, stream, ei, ej, bA, sA);
    hipLaunchKernelGGL(pv_kernel,  dim3(8, 128),  dim3(512), 0, stream, WhT, ei, ej, sA, bA, out);
}

// Round 3
// 373.295 us; speedup vs baseline: 1.0105x; 1.0105x over previous
//
#include <hip/hip_runtime.h>

// GAT fused pipeline, fp16 MFMA (16x16x32), MI355X gfx950.
// B=16, N=1024, F_in=F_out=256, H=8, ALPHA=0.2
//
// ws layout:
//   [0, 64MB)        WhT fp16  [B][H][F_out][N]   (Wh transposed)
//   +67108864        ei  f32   [B*H*N]
//   +67633152        ej  f32   [B*H*N]
//   +68157440        s   f32   [B*H*N]   s = m*log2e + log2(l)

#define FIN  256
#define FOUT 256
#define NN   1024
#define HH   8
#define L2E  1.442695041f

typedef _Float16 half8 __attribute__((ext_vector_type(8)));
typedef __fp16 fp16x2 __attribute__((ext_vector_type(2)));
typedef float floatx4 __attribute__((ext_vector_type(4)));

#if __has_builtin(__builtin_amdgcn_exp2f)
#define EXP2F(x) __builtin_amdgcn_exp2f(x)
#else
#define EXP2F(x) exp2f(x)
#endif

static __device__ inline unsigned int pack2(float a, float b) {
    fp16x2 h = __builtin_amdgcn_cvt_pkrtz(a, b);
    return __builtin_bit_cast(unsigned int, h);
}

// ---------------------------------------------------------------------------
// Stage 1: WhT[b,h,o,n] = sum_f W[h,o,f]*h[b,n,f] + bW[h,o]   (fp16 out)
// + fused ei/ej epilogue: ei[bh,n] = sum_o Wh*a1 (fp32 acc), likewise ej.
// GEMM: M=o(256 full), Ntile=bn(128), K=f(256), BK=32. 512 thr = 8 waves.
__global__ __launch_bounds__(512, 2) void wh_kernel(
    const float* __restrict__ hin, const float* __restrict__ W,
    const float* __restrict__ bW, _Float16* __restrict__ WhT,
    const float* __restrict__ a1, const float* __restrict__ a2,
    float* __restrict__ ei, float* __restrict__ ej)
{
    const int bnt  = blockIdx.x;   // 0..127
    const int head = blockIdx.y;   // 0..7
    const int t    = threadIdx.x;
    const int wave = t >> 6, lane = t & 63;
    const int l15 = lane & 15, quad = lane >> 4;

    __shared__ _Float16 Asm[256 * 40];  // W tile [o][kk], pitch 40 f16 (80B)
    __shared__ _Float16 Bsm[128 * 40];  // h tile [n][kk], pitch 40
    __shared__ float bWs[256], a1s[256], a2s[256];
    __shared__ float red1[128], red2[128];
    if (t < 256) {
        bWs[t] = bW[head * FOUT + t];
        a1s[t] = a1[head * FOUT + t];
        a2s[t] = a2[head * FOUT + t];
    }
    if (t < 128) { red1[t] = 0.f; red2[t] = 0.f; }

    const int bn0 = bnt * 128;
    floatx4 acc[4][4];
#pragma unroll
    for (int a = 0; a < 4; a++)
#pragma unroll
        for (int b = 0; b < 4; b++) acc[a][b] = (floatx4)0.0f;

    const int wm = (wave & 3) * 4;   // of 16 m-tiles (o)
    const int wn = (wave >> 2) * 4;  // of 8 n-tiles (bn)

    const int ao = t >> 1, ahalf = (t & 1) * 16;   // A staging: 16 floats
    const int bnr = t >> 2, bq = (t & 3) * 8;      // B staging: 8 floats
    const float* Wrow = W + (size_t)(head * FOUT + ao) * FIN + ahalf;
    const float* hrow = hin + (size_t)(bn0 + bnr) * FIN + bq;

    for (int f0 = 0; f0 < FIN; f0 += 32) {
        __syncthreads();
        {   // stage A (W -> fp16)
            const float4* p4 = (const float4*)(Wrow + f0);
            float4 v0 = p4[0], v1 = p4[1], v2 = p4[2], v3 = p4[3];
            uint4* dst = (uint4*)((char*)Asm + ao * 80 + ahalf * 2);
            dst[0] = make_uint4(pack2(v0.x, v0.y), pack2(v0.z, v0.w),
                                pack2(v1.x, v1.y), pack2(v1.z, v1.w));
            dst[1] = make_uint4(pack2(v2.x, v2.y), pack2(v2.z, v2.w),
                                pack2(v3.x, v3.y), pack2(v3.z, v3.w));
        }
        {   // stage B (h -> fp16)
            const float4* p4 = (const float4*)(hrow + f0);
            float4 v0 = p4[0], v1 = p4[1];
            uint4* dst = (uint4*)((char*)Bsm + bnr * 80 + bq * 2);
            dst[0] = make_uint4(pack2(v0.x, v0.y), pack2(v0.z, v0.w),
                                pack2(v1.x, v1.y), pack2(v1.z, v1.w));
        }
        __syncthreads();
        half8 af[4], bf[4];
#pragma unroll
        for (int a = 0; a < 4; a++)
            af[a] = *(const half8*)((char*)Asm + ((wm + a) * 16 + l15) * 80 + quad * 16);
#pragma unroll
        for (int b = 0; b < 4; b++)
            bf[b] = *(const half8*)((char*)Bsm + ((wn + b) * 16 + l15) * 80 + quad * 16);
#pragma unroll
        for (int a = 0; a < 4; a++)
#pragma unroll
            for (int b = 0; b < 4; b++)
                acc[a][b] = __builtin_amdgcn_mfma_f32_16x16x32_f16(af[a], bf[b], acc[a][b], 0, 0, 0);
    }

    // epilogue: +bW, cvt fp16, store WhT; accumulate ei/ej partials in LDS
    const int bidx = bn0 >> 10;          // batch (bn-tile never crosses batch)
    const int nbase = bn0 & 1023;
#pragma unroll
    for (int b = 0; b < 4; b++) {
        const int bnl = (wn + b) * 16 + l15;     // local bn 0..127
        const int n = nbase + bnl;
        float p1 = 0.f, p2 = 0.f;
#pragma unroll
        for (int a = 0; a < 4; a++) {
#pragma unroll
            for (int r = 0; r < 4; r++) {
                int o = (wm + a) * 16 + quad * 4 + r;
                float v = acc[a][b][r] + bWs[o];
                WhT[(((size_t)(bidx * HH + head) * FOUT + o) << 10) + n] = (_Float16)v;
                p1 = fmaf(v, a1s[o], p1);
                p2 = fmaf(v, a2s[o], p2);
            }
        }
        atomicAdd(&red1[bnl], p1);
        atomicAdd(&red2[bnl], p2);
    }
    __syncthreads();
    if (t < 128) {
        const int n = nbase + t;
        const size_t idx = (size_t)(bidx * HH + head) * NN + n;
        ei[idx] = red1[t];
        ej[idx] = red2[t];
    }
}

// ---------------------------------------------------------------------------
// Stage 2: per row i: m = lrelu(ci + ejmax), l = sum_j exp(lrelu(ci+ej[j])-m)
//          s = m*log2e + log2(l).  ci = ei[i] + bA[h].
__global__ __launch_bounds__(256) void ml_kernel(
    const float* __restrict__ ei, const float* __restrict__ ej,
    const float* __restrict__ bA, float* __restrict__ sarr)
{
    const int it = blockIdx.x;   // i-chunk of 128
    const int bh = blockIdx.y;
    const int head = bh & 7;
    const int t = threadIdx.x;
    __shared__ float ejs[1024];
    __shared__ float red[256];
    const float* ejrow = ej + bh * 1024;
    float mx = -1e30f;
#pragma unroll
    for (int k = 0; k < 4; k++) {
        float v = ejrow[t + k * 256];
        ejs[t + k * 256] = v;
        mx = fmaxf(mx, v);
    }
    red[t] = mx;
    __syncthreads();
    for (int sft = 128; sft > 0; sft >>= 1) {
        if (t < sft) red[t] = fmaxf(red[t], red[t + sft]);
        __syncthreads();
    }
    const float ejmax = red[0];
    __syncthreads();

    const int i = it * 128 + (t & 127);
    const int half = t >> 7;
    const float ci = ei[bh * 1024 + i] + bA[head];
    float tm = ci + ejmax;
    float m = fmaxf(tm, 0.2f * tm);
    float sum = 0.f;
    const int j0 = half * 512;
    for (int j = j0; j < j0 + 512; j++) {
        float e = ci + ejs[j];
        float lr = fmaxf(e, 0.2f * e);
        sum += EXP2F((lr - m) * L2E);
    }
    red[t] = sum;
    __syncthreads();
    if (t < 128) {
        float l = red[t] + red[t + 128];
        sarr[bh * 1024 + i] = m * L2E + __log2f(l);
    }
}

// ---------------------------------------------------------------------------
// Stage 3: out[b,i,h*256+o] = sigmoid(relu( sum_j p_ij * Wh[j,o] ))
// p_ij = exp2(lrelu(ci+ej[j])*log2e - s_i), generated on the fly into LDS.
// Tile 128(i) x 256(o), K=1024(j) in BK=32. 512 thr = 8 waves.
// Grid: x=bh (fast) so all 8 i-tiles of one bh land on one XCD (id%8=bh%8)
// -> WhT[bh] slice (512KB) stays hot in that XCD's L2.
__global__ __launch_bounds__(512, 2) void pv_kernel(
    const _Float16* __restrict__ WhT, const float* __restrict__ ei,
    const float* __restrict__ ej, const float* __restrict__ sarr,
    const float* __restrict__ bA, float* __restrict__ out)
{
    const int bh = blockIdx.x;   // 0..127  (fast dim -> XCD key)
    const int it = blockIdx.y;   // 0..7
    const int b = bh >> 3, head = bh & 7;
    const int t = threadIdx.x;
    const int wave = t >> 6, lane = t & 63;
    const int l15 = lane & 15, quad = lane >> 4;

    __shared__ _Float16 Ap[128 * 40];   // P tile [i][kk], pitch 40
    __shared__ _Float16 Bp[256 * 40];   // WhT tile [o][kk], pitch 40
    __shared__ float ejs[1024];

    const float* ejrow = ej + bh * 1024;
    for (int k = t; k < 1024; k += 512) ejs[k] = ejrow[k];

    const int i0 = it * 128;
    const int irow = t & 127;        // p-compute row
    const int kk8 = (t >> 7) * 8;    // p-compute kk base: 0/8/16/24
    const int gi = i0 + irow;
    const float ci = ei[bh * 1024 + gi] + bA[head];
    const float ns = -sarr[bh * 1024 + gi];

    const int bo = t >> 1;            // B staging row (o): 0..255
    const int bhalf = (t & 1) * 16;   // 16 f16 per thread
    const _Float16* wrow = WhT + ((size_t)bh << 18) + ((size_t)bo << 10) + bhalf;

    floatx4 acc[2][8];
#pragma unroll
    for (int a = 0; a < 2; a++)
#pragma unroll
        for (int c = 0; c < 8; c++) acc[a][c] = (floatx4)0.0f;

    const int wm = (wave >> 1) * 2;  // of 8 m-tiles
    const int wn = (wave & 1) * 8;   // of 16 n-tiles

    for (int j0 = 0; j0 < 1024; j0 += 32) {
        __syncthreads();
        {   // stage P tile
            float p[8];
#pragma unroll
            for (int u = 0; u < 8; u++) {
                float e = ci + ejs[j0 + kk8 + u];
                float lr = fmaxf(e, 0.2f * e);
                p[u] = EXP2F(fmaf(lr, L2E, ns));
            }
            uint4* dst = (uint4*)((char*)Ap + irow * 80 + kk8 * 2);
            *dst = make_uint4(pack2(p[0], p[1]), pack2(p[2], p[3]),
                              pack2(p[4], p[5]), pack2(p[6], p[7]));
        }
        {   // stage B tile (fp16 direct copy)
            const uint4* src = (const uint4*)(wrow + j0);
            uint4 v0 = src[0], v1 = src[1];
            uint4* dst = (uint4*)((char*)Bp + bo * 80 + bhalf * 2);
            dst[0] = v0; dst[1] = v1;
        }
        __syncthreads();
        half8 af[2], bf[8];
#pragma unroll
        for (int a = 0; a < 2; a++)
            af[a] = *(const half8*)((char*)Ap + ((wm + a) * 16 + l15) * 80 + quad * 16);
#pragma unroll
        for (int c = 0; c < 8; c++)
            bf[c] = *(const half8*)((char*)Bp + ((wn + c) * 16 + l15) * 80 + quad * 16);
#pragma unroll
        for (int a = 0; a < 2; a++)
#pragma unroll
            for (int c = 0; c < 8; c++)
                acc[a][c] = __builtin_amdgcn_mfma_f32_16x16x32_f16(af[a], bf[c], acc[a][c], 0, 0, 0);
    }

    // epilogue: relu + sigmoid, out[b, i, head*256 + o]
#pragma unroll
    for (int a = 0; a < 2; a++) {
#pragma unroll
        for (int c = 0; c < 8; c++) {
            int o = (wn + c) * 16 + l15;
#pragma unroll
            for (int r = 0; r < 4; r++) {
                int i = i0 + (wm + a) * 16 + quad * 4 + r;
                float v = acc[a][c][r];
                float rl = fmaxf(v, 0.0f);
                float y = 1.0f / (1.0f + EXP2F(-rl * L2E));
                out[((size_t)(b * 1024 + i) << 11) + head * 256 + o] = y;
            }
        }
    }
}

// ---------------------------------------------------------------------------
extern "C" void kernel_launch(void* const* d_in, const int* in_sizes, int n_in,
                              void* d_out, int out_size, void* d_ws, size_t ws_size,
                              hipStream_t stream)
{
    const float* h  = (const float*)d_in[0];
    const float* W  = (const float*)d_in[1];
    const float* bW = (const float*)d_in[2];
    const float* a1 = (const float*)d_in[3];
    const float* a2 = (const float*)d_in[4];
    const float* bA = (const float*)d_in[5];
    float* out = (float*)d_out;

    char* ws = (char*)d_ws;
    _Float16* WhT = (_Float16*)ws;                       // 67108864 B
    float* ei = (float*)(ws + 67108864);
    float* ej = (float*)(ws + 67108864 + 524288);
    float* sA = (float*)(ws + 67108864 + 2 * 524288);

    hipLaunchKernelGGL(wh_kernel, dim3(128, 8), dim3(512), 0, stream,
                       h, W, bW, WhT, a1, a2, ei, ej);
    hipLaunchKernelGGL(ml_kernel, dim3(8, 128), dim3(256), 0, stream, ei, ej, bA, sA);
    hipLaunchKernelGGL(pv_kernel, dim3(128, 8), dim3(512), 0, stream,
                       WhT, ei, ej, sA, bA, out);
}